// Round 3
// baseline (431.831 us; speedup 1.0000x reference)
//
#include <hip/hip_runtime.h>

// GroupedQueryAttention: B=2, S=2048, HIDDEN=2048, NH=16, NKV=4, HD=128, G=4
// R3: barrier-free 1-wave attention blocks; K/V stored in MFMA fragment-order by the
//     QKV GEMM epilogue so attention staging is pure global_load_lds 1KB chunks and
//     every LDS access is lane-contiguous (conflict-free, unpadded). k_tv dropped.

#define SEQ    2048
#define HIDDEN 2048

typedef __attribute__((ext_vector_type(8))) short v8s;   // 8 x bf16 (4 VGPRs)
typedef __attribute__((ext_vector_type(4))) float v4f;   // MFMA accumulator

#define MFMA16(a,b,c) __builtin_amdgcn_mfma_f32_16x16x32_bf16((a),(b),(c),0,0,0)

__device__ __forceinline__ ushort f2b(float f){
  unsigned u = __float_as_uint(f);
  u += 0x7fffu + ((u >> 16) & 1u);       // round-to-nearest-even
  return (ushort)(u >> 16);
}

__device__ __forceinline__ void gload16(const void* g, void* l){
  __builtin_amdgcn_global_load_lds((const __attribute__((address_space(1))) void*)g,
                                   (__attribute__((address_space(3))) void*)l, 16, 0, 0);
}

// s_waitcnt immediates (gfx9 encoding): vmcnt[3:0]@0, expcnt@4, lgkmcnt@8, vmcnt[5:4]@14
#define WAIT_VM0   0x0F70   // vmcnt(0), others don't-care
#define WAIT_LGKM0 0xC07F   // lgkmcnt(0), others don't-care

// ---------- fp32 -> bf16, 4 elems/thread ----------
__global__ void k_conv(const float* __restrict__ in, ushort* __restrict__ out, int n){
  int i = (blockIdx.x*256 + threadIdx.x)*4;
  if (i >= n) return;
  float4 f = *(const float4*)(in + i);
  ushort4 u; u.x=f2b(f.x); u.y=f2b(f.y); u.z=f2b(f.z); u.w=f2b(f.w);
  *(ushort4*)(out + i) = u;
}

// ---------- fp32 (rows x cols) -> bf16 (cols x rows), LDS-tiled ----------
__global__ void k_tconv(const float* __restrict__ in, ushort* __restrict__ out,
                        int rows, int cols){
  __shared__ float t[32][33];
  int tx = threadIdx.x & 31, ty = threadIdx.x >> 5;
  int c0 = blockIdx.x*32, r0 = blockIdx.y*32;
#pragma unroll
  for (int i=0;i<4;i++) t[ty+i*8][tx] = in[(size_t)(r0+ty+i*8)*cols + c0+tx];
  __syncthreads();
#pragma unroll
  for (int i=0;i<4;i++) out[(size_t)(c0+ty+i*8)*rows + r0+tx] = f2b(t[tx][ty+i*8]);
}

// ---------- GEMM mainloop: 128x128 tile, BK=32, global_load_lds staging ----------
#define GEMM_MAIN(A_, Bt_, K_)                                                        \
  __shared__ ushort sA[128*32], sB[128*32];                                           \
  const int tid = threadIdx.x, lane = tid & 63, wid = tid >> 6;                       \
  const int wm = wid >> 1, wn = wid & 1, lm = lane & 15, q8 = (lane >> 4)*8;          \
  const int rowB = blockIdx.y*128, colB = blockIdx.x*128;                             \
  v4f acc[4][4] = {};                                                                 \
  for (int k0 = 0; k0 < (K_); k0 += 32){                                              \
    _Pragma("unroll")                                                                 \
    for (int it=0; it<2; it++){                                                       \
      int c = tid + it*256;                                                           \
      gload16((A_)  + (size_t)(rowB + (c>>2))*(K_) + k0 + (c&3)*8, (char*)sA + c*16); \
      gload16((Bt_) + (size_t)(colB + (c>>2))*(K_) + k0 + (c&3)*8, (char*)sB + c*16); \
    }                                                                                 \
    __syncthreads();                                                                  \
    v8s af[4], bfr[4];                                                                \
    _Pragma("unroll")                                                                 \
    for (int i=0;i<4;i++){                                                            \
      af[i]  = *(const v8s*)(sA + (wm*64 + i*16 + lm)*32 + q8);                       \
      bfr[i] = *(const v8s*)(sB + (wn*64 + i*16 + lm)*32 + q8);                       \
    }                                                                                 \
    _Pragma("unroll")                                                                 \
    for (int i=0;i<4;i++)                                                             \
      _Pragma("unroll")                                                               \
      for (int j=0;j<4;j++) acc[i][j] = MFMA16(af[i], bfr[j], acc[i][j]);             \
    __syncthreads();                                                                  \
  }                                                                                   \
  const int quad = lane >> 4;

// QKV GEMM: M=4096, N=3072(q|k|v), K=2048.
// Epilogue: Q -> row-major qb; K,V -> attention fragment-order kbF/vbF:
//   kbF[(b*4+hkv)*262144 + (s>>5)*4096 + (((s>>4)&1)*4 + d>>5)*512
//       + (((d>>3)&3)*16 + (s&15))*8 + (d&7)]
//   vbF[(b*4+hkv)*262144 + (s>>5)*4096 + (d>>4)*512
//       + (((s>>3)&3)*16 + (d&15))*8 + (s&7)]
__global__ __launch_bounds__(256) void k_gemm_qkv(
    const ushort* __restrict__ A, const ushort* __restrict__ Bt,
    const float* __restrict__ bq, const float* __restrict__ bk, const float* __restrict__ bv,
    ushort* __restrict__ qb, ushort* __restrict__ kbF, ushort* __restrict__ vbF){
  GEMM_MAIN(A, Bt, HIDDEN)
#pragma unroll
  for (int i=0;i<4;i++)
#pragma unroll
  for (int j=0;j<4;j++){
    int col = colB + wn*64 + j*16 + lm;
#pragma unroll
    for (int r=0;r<4;r++){
      int row = rowB + wm*64 + i*16 + quad*4 + r;
      int b = row >> 11, s = row & 2047;
      float v = acc[i][j][r];
      if (col < 2048){
        qb[(size_t)row*2048 + col] = f2b(v + bq[col]);
      } else if (col < 2560){
        int c = col - 2048, hkv = c >> 7, d = c & 127;
        size_t a = (size_t)(b*4+hkv)*262144 + (size_t)(s>>5)*4096
                 + (size_t)((((s>>4)&1)*4) + (d>>5))*512
                 + (size_t)((((d>>3)&3)*16 + (s&15))*8) + (d&7);
        kbF[a] = f2b(v + bk[c]);
      } else {
        int c = col - 2560, hkv = c >> 7, d = c & 127;
        size_t a = (size_t)(b*4+hkv)*262144 + (size_t)(s>>5)*4096
                 + (size_t)(d>>4)*512
                 + (size_t)((((s>>3)&3)*16 + (d&15))*8) + (s&7);
        vbF[a] = f2b(v + bv[c]);
      }
    }
  }
}

// Output GEMM: M=4096, N=2048, K=2048; fp32 out + bias
__global__ __launch_bounds__(256) void k_gemm_out(
    const ushort* __restrict__ A, const ushort* __restrict__ Bt,
    const float* __restrict__ bo, float* __restrict__ out){
  GEMM_MAIN(A, Bt, HIDDEN)
#pragma unroll
  for (int i=0;i<4;i++)
#pragma unroll
  for (int j=0;j<4;j++){
    int col = colB + wn*64 + j*16 + lm;
#pragma unroll
    for (int r=0;r<4;r++){
      int row = rowB + wm*64 + i*16 + quad*4 + r;
      out[(size_t)row*2048 + col] = acc[i][j][r] + bo[col];
    }
  }
}

// ---------- Flash attention, barrier-free ----------
// grid (64 qt, 16 heads, 2 b), 64 threads = 1 wave. Wave owns 32 q-rows; 32-key
// tiles, 64 iters. K tile 8KB + V tile 8KB staged via global_load_lds from
// fragment-order buffers (1KB lane-contiguous chunks). S^T = MFMA(A=K,B=Q) ->
// lane-local softmax; P packed uint2 into sK alias (chunks 0,1), read back as
// A-operand. All ordering via in-wave s_waitcnt — zero s_barrier.
__global__ __launch_bounds__(64,2) void k_attn(
    const ushort* __restrict__ qb, const ushort* __restrict__ kbF,
    const ushort* __restrict__ vbF, ushort* __restrict__ Ob){
  __shared__ ushort sK[4096];   // K chunks (ct2 x ks4) x 512; P alias in chunks 0,1
  __shared__ ushort sV[4096];   // V chunks (dt8) x 512
  const int lane = threadIdx.x;
  const int lm = lane & 15, quad = lane >> 4, q8 = quad*8;
  const int qt = blockIdx.x, head = blockIdx.y, b = blockIdx.z;
  const int hkv = head >> 2;
  const float C = 0.08838834764831845f * 1.4426950408889634f;  // SCALE * log2(e)

  const ushort* kbase = kbF + (size_t)(b*4+hkv)*262144;
  const ushort* vbase = vbF + (size_t)(b*4+hkv)*262144;

  // Q fragments (B-operand): qrow = qt*32 + rb*16 + lm, k = d
  v8s qf[2][4];
#pragma unroll
  for (int rb=0; rb<2; rb++)
#pragma unroll
    for (int ks=0; ks<4; ks++)
      qf[rb][ks] = *(const v8s*)(qb + (size_t)(b*SEQ + qt*32 + rb*16 + lm)*HIDDEN
                                    + head*128 + ks*32 + q8);

  v4f o[2][8] = {};
  float mreg[2] = {-3e38f, -3e38f};
  float lreg[2] = {0.f, 0.f};

  for (int t2=0; t2<64; t2++){
    // prior iter's ds_reads must have landed before DMA overwrites LDS
    __builtin_amdgcn_s_waitcnt(WAIT_LGKM0);
    const ushort* kc = kbase + t2*4096;
    const ushort* vc = vbase + t2*4096;
#pragma unroll
    for (int c=0; c<8; c++) gload16(kc + c*512 + lane*8, sK + c*512 + lane*8);
#pragma unroll
    for (int c=0; c<8; c++) gload16(vc + c*512 + lane*8, sV + c*512 + lane*8);
    __builtin_amdgcn_s_waitcnt(WAIT_VM0);

    // S^T: sacc[rb][ct]; key = ct*16 + quad*4 + r, qrow = rb*16 + lm
    v4f sacc[2][2] = {};
#pragma unroll
    for (int ct=0; ct<2; ct++){
      v8s kf[4];
#pragma unroll
      for (int ks=0; ks<4; ks++) kf[ks] = *(const v8s*)(sK + (ct*4+ks)*512 + lane*8);
#pragma unroll
      for (int rb=0; rb<2; rb++)
#pragma unroll
        for (int ks=0; ks<4; ks++) sacc[rb][ct] = MFMA16(kf[ks], qf[rb][ks], sacc[rb][ct]);
    }

    // online softmax; P -> sK alias chunks rb (A-frag order)
    float alpha[2];
#pragma unroll
    for (int rb=0; rb<2; rb++){
      float mx = mreg[rb];
#pragma unroll
      for (int ct=0; ct<2; ct++)
#pragma unroll
        for (int r=0;r<4;r++) mx = fmaxf(mx, sacc[rb][ct][r]);
      mx = fmaxf(mx, __shfl_xor(mx, 16));
      mx = fmaxf(mx, __shfl_xor(mx, 32));
      alpha[rb] = __builtin_amdgcn_exp2f((mreg[rb]-mx)*C);
      mreg[rb] = mx;
      float mxC = mx*C, rs = 0.f;
#pragma unroll
      for (int ct=0; ct<2; ct++){
        float p0 = __builtin_amdgcn_exp2f(fmaf(sacc[rb][ct][0], C, -mxC));
        float p1 = __builtin_amdgcn_exp2f(fmaf(sacc[rb][ct][1], C, -mxC));
        float p2 = __builtin_amdgcn_exp2f(fmaf(sacc[rb][ct][2], C, -mxC));
        float p3 = __builtin_amdgcn_exp2f(fmaf(sacc[rb][ct][3], C, -mxC));
        rs += (p0+p1)+(p2+p3);
        uint2 pk;
        pk.x = (unsigned)f2b(p0) | ((unsigned)f2b(p1) << 16);
        pk.y = (unsigned)f2b(p2) | ((unsigned)f2b(p3) << 16);
        // element (qrow=lm, key=ct*16+quad*4+r) -> chunk rb, lane (ct*2+(quad>>1))*16+lm, j0=(quad&1)*4
        int dstlane = (ct*2 + (quad>>1))*16 + lm;
        *(uint2*)(sK + rb*512 + dstlane*8 + (quad&1)*4) = pk;
      }
      rs += __shfl_xor(rs, 16);
      rs += __shfl_xor(rs, 32);
      lreg[rb] = lreg[rb]*alpha[rb] + rs;
    }

    // rescale O (o qrow = rbo*16 + quad*4 + r; alpha lives at lane lm=qrow)
#pragma unroll
    for (int rbo=0; rbo<2; rbo++)
#pragma unroll
      for (int r=0;r<4;r++){
        float a = __shfl(alpha[rbo], (lane & 48) + quad*4 + r);
#pragma unroll
        for (int dt=0; dt<8; dt++) o[rbo][dt][r] *= a;
      }

    // O += P V   (pa: A-frag from sK alias; vf: B-frag chunks from sV)
    __builtin_amdgcn_s_waitcnt(WAIT_LGKM0);   // P writes visible to own reads
    v8s pa[2];
#pragma unroll
    for (int rb=0; rb<2; rb++) pa[rb] = *(const v8s*)(sK + rb*512 + lane*8);
#pragma unroll
    for (int dt=0; dt<8; dt++){
      v8s vf = *(const v8s*)(sV + dt*512 + lane*8);
#pragma unroll
      for (int rbo=0; rbo<2; rbo++) o[rbo][dt] = MFMA16(pa[rbo], vf, o[rbo][dt]);
    }
  }

  // epilogue: normalize (l lives at lane lm=qrow), write bf16 O
#pragma unroll
  for (int rbo=0; rbo<2; rbo++){
    float inv[4];
#pragma unroll
    for (int r=0;r<4;r++) inv[r] = 1.0f / __shfl(lreg[rbo], (lane & 48) + quad*4 + r);
#pragma unroll
    for (int dt=0; dt<8; dt++)
#pragma unroll
      for (int r=0;r<4;r++){
        int row = b*SEQ + qt*32 + rbo*16 + quad*4 + r;
        int col = head*128 + dt*16 + lm;
        Ob[(size_t)row*HIDDEN + col] = f2b(o[rbo][dt][r]*inv[r]);
      }
  }
}

extern "C" void kernel_launch(void* const* d_in, const int* in_sizes, int n_in,
                              void* d_out, int out_size, void* d_ws, size_t ws_size,
                              hipStream_t stream){
  const float* x  = (const float*)d_in[0];
  const float* Wq = (const float*)d_in[1];
  const float* bq = (const float*)d_in[2];
  const float* Wk = (const float*)d_in[3];
  const float* bk = (const float*)d_in[4];
  const float* Wv = (const float*)d_in[5];
  const float* bv = (const float*)d_in[6];
  const float* Wo = (const float*)d_in[7];
  const float* bo = (const float*)d_in[8];
  float* out = (float*)d_out;

  // workspace layout (bf16 elems): 39.8M ushorts = 79.7 MB
  ushort* xb  = (ushort*)d_ws;        // 4096x2048
  ushort* Wt  = xb  + 8388608;        // 3072x2048  (Wq^T | Wk^T | Wv^T)
  ushort* Wto = Wt  + 6291456;        // 2048x2048  (Wo^T)
  ushort* qb  = Wto + 4194304;        // 4096x2048 row-major
  ushort* kbF = qb  + 8388608;        // K fragment-order, 2x4x(64 tiles)x4096
  ushort* vbF = kbF + 2097152;        // V fragment-order
  ushort* Ob  = vbF + 2097152;        // 4096x2048

  k_conv <<<8192, 256, 0, stream>>>(x, xb, 8388608);
  k_tconv<<<dim3(64,64), 256, 0, stream>>>(Wq, Wt, 2048, 2048);
  k_tconv<<<dim3(16,64), 256, 0, stream>>>(Wk, Wt + 4194304, 2048, 512);
  k_tconv<<<dim3(16,64), 256, 0, stream>>>(Wv, Wt + 5242880, 2048, 512);
  k_tconv<<<dim3(64,64), 256, 0, stream>>>(Wo, Wto, 2048, 2048);
  k_gemm_qkv<<<dim3(24,32), 256, 0, stream>>>(xb, Wt, bq, bk, bv, qb, kbF, vbF);
  k_attn<<<dim3(64,16,2), 64, 0, stream>>>(qb, kbF, vbF, Ob);
  k_gemm_out<<<dim3(16,32), 256, 0, stream>>>(Ob, Wto, bo, out);
}